// Round 7
// baseline (784.141 us; speedup 1.0000x reference)
//
#include <hip/hip_runtime.h>
#include <hip/hip_bf16.h>
#include <stdint.h>

// Problem constants
#define B_SZ 32
#define F_SZ 40
#define NB_SZ 36
#define R_SZ 512
#define H_SZ 512
#define D_SZ 1536
#define M1 (B_SZ * F_SZ * NB_SZ)   // 46080
#define NROW (B_SZ * F_SZ)         // 1280
#define FNB (F_SZ * NB_SZ)         // 1440

#define LDV 68  // fp32 tile leading dim (+4 pad)

__device__ __forceinline__ unsigned short f2bf(float f) {
    unsigned int x = __float_as_uint(f);
    return (unsigned short)((x + 0x7fffu + ((x >> 16) & 1u)) >> 16);  // RNE
}
__device__ __forceinline__ float bf2f(unsigned short u) {
    union { unsigned int i; float f; } v; v.i = ((unsigned int)u) << 16; return v.f;
}

// ---------------------------------------------------------------------------
// hs[b,h] = hidden[b]@Ws_h.T + bs_h + bs_f ; hr[b,h] = hidden[b]@Wr_h.T + br_h + br_f
// ---------------------------------------------------------------------------
__global__ __launch_bounds__(256) void k_hproj(
    const float* __restrict__ hidden,
    const float* __restrict__ Wsh, const float* __restrict__ bsh,
    const float* __restrict__ bsf,
    const float* __restrict__ Wrh, const float* __restrict__ brh,
    const float* __restrict__ brf,
    float* __restrict__ hs, float* __restrict__ hr)
{
    __shared__ float hid[H_SZ];
    const int b = blockIdx.x, t = threadIdx.x;
    for (int i = t; i < H_SZ; i += 256) hid[i] = hidden[b * H_SZ + i];
    __syncthreads();
    for (int h = t; h < H_SZ; h += 256) {
        float a1 = bsh[h] + bsf[h];
        float a2 = brh[h] + brf[h];
        const float* r1 = Wsh + (size_t)h * H_SZ;
        const float* r2 = Wrh + (size_t)h * H_SZ;
        for (int k = 0; k < H_SZ; k += 4) {
            float4 v1 = *(const float4*)(r1 + k);
            float4 v2 = *(const float4*)(r2 + k);
            a1 += hid[k] * v1.x + hid[k+1] * v1.y + hid[k+2] * v1.z + hid[k+3] * v1.w;
            a2 += hid[k] * v2.x + hid[k+1] * v2.y + hid[k+2] * v2.z + hid[k+3] * v2.w;
        }
        hs[b * H_SZ + h] = a1;
        hr[b * H_SZ + h] = a2;
    }
}

// ---------------------------------------------------------------------------
// e1[m] = sum_h tanh( feats[m,:]@Wsf[h,:] + hs[b(m),h] ) * was[h]   (fp32 VALU)
// ---------------------------------------------------------------------------
__global__ __launch_bounds__(256) void k_e1_valu(
    const float* __restrict__ feats,  // (46080, 512)
    const float* __restrict__ Wsf,    // (512, 512)
    const float* __restrict__ was,    // (512)
    const float* __restrict__ hs,     // (32, 512)
    float* __restrict__ e1)           // (46080)
{
    __shared__ __align__(16) float As[64 * LDV];
    __shared__ __align__(16) float Bs[64 * LDV];
    __shared__ float hsl[2 * H_SZ];
    __shared__ float wasl[H_SZ];

    const int t = threadIdx.x;
    const int tx = t & 15, ty = t >> 4;
    const int m0 = blockIdx.x * 64;
    const int b0 = m0 / FNB, b1 = (m0 + 63) / FNB;

    for (int i = t; i < H_SZ; i += 256) {
        hsl[i]        = hs[b0 * H_SZ + i];
        hsl[H_SZ + i] = hs[b1 * H_SZ + i];
        wasl[i]       = was[i];
    }

    int bo[4];
#pragma unroll
    for (int i = 0; i < 4; i++) {
        int m = m0 + i * 16 + ty;
        bo[i] = (m / FNB == b0) ? 0 : H_SZ;
    }

    float ep[4] = {0.f, 0.f, 0.f, 0.f};

    for (int h0 = 0; h0 < 512; h0 += 64) {
        float acc[4][4];
#pragma unroll
        for (int i = 0; i < 4; i++)
#pragma unroll
            for (int j = 0; j < 4; j++) acc[i][j] = 0.f;

        for (int k0 = 0; k0 < 512; k0 += 64) {
            __syncthreads();
#pragma unroll
            for (int it = 0; it < 4; it++) {
                int idx = it * 256 + t;
                int row = idx >> 4, cc = idx & 15;
                *(float4*)(As + row * LDV + cc * 4) =
                    *(const float4*)(feats + (size_t)(m0 + row) * R_SZ + k0 + cc * 4);
                *(float4*)(Bs + row * LDV + cc * 4) =
                    *(const float4*)(Wsf + (size_t)(h0 + row) * R_SZ + k0 + cc * 4);
            }
            __syncthreads();

            for (int k = 0; k < 64; k += 4) {
                float4 a4[4], b4[4];
#pragma unroll
                for (int i = 0; i < 4; i++) a4[i] = *(const float4*)(As + (i * 16 + ty) * LDV + k);
#pragma unroll
                for (int j = 0; j < 4; j++) b4[j] = *(const float4*)(Bs + (j * 16 + tx) * LDV + k);
#pragma unroll
                for (int i = 0; i < 4; i++)
#pragma unroll
                    for (int j = 0; j < 4; j++) {
                        acc[i][j] += a4[i].x * b4[j].x;
                        acc[i][j] += a4[i].y * b4[j].y;
                        acc[i][j] += a4[i].z * b4[j].z;
                        acc[i][j] += a4[i].w * b4[j].w;
                    }
            }
        }
#pragma unroll
        for (int j = 0; j < 4; j++) {
            int h = h0 + j * 16 + tx;
            float wv = wasl[h];
#pragma unroll
            for (int i = 0; i < 4; i++)
                ep[i] += tanhf(acc[i][j] + hsl[bo[i] + h]) * wv;
        }
    }
#pragma unroll
    for (int i = 0; i < 4; i++) {
        float v = ep[i];
        v += __shfl_xor(v, 1);
        v += __shfl_xor(v, 2);
        v += __shfl_xor(v, 4);
        v += __shfl_xor(v, 8);
        if (tx == 0) e1[m0 + i * 16 + ty] = v;
    }
}

// ---------------------------------------------------------------------------
// per n: softmax over 36 e1's, att = alpha-weighted sum of feats rows,
// feat[n] = [att(512) | i3d(1024)] bf16 (internal staging format)
// ---------------------------------------------------------------------------
__global__ __launch_bounds__(256) void k_softatt(
    const float* __restrict__ feats,
    const float* __restrict__ i3d,
    const float* __restrict__ e1,
    unsigned short* __restrict__ feat)
{
    __shared__ float alpha[NB_SZ];
    const int n = blockIdx.x, t = threadIdx.x;
    if (t < 64) {
        float v = (t < NB_SZ) ? e1[n * NB_SZ + t] : -1e30f;
        float m = v;
#pragma unroll
        for (int off = 32; off; off >>= 1) m = fmaxf(m, __shfl_xor(m, off));
        float ex = (t < NB_SZ) ? expf(v - m) : 0.f;
        float ssum = ex;
#pragma unroll
        for (int off = 32; off; off >>= 1) ssum += __shfl_xor(ssum, off);
        if (t < NB_SZ) alpha[t] = ex / ssum;
    }
    __syncthreads();

    float a0 = 0.f, a1 = 0.f;
    const float* base = feats + (size_t)n * NB_SZ * R_SZ;
    for (int ll = 0; ll < NB_SZ; ll++) {
        float al = alpha[ll];
        float2 pv = *(const float2*)(base + ll * R_SZ + 2 * t);
        a0 += al * pv.x;
        a1 += al * pv.y;
    }
    feat[(size_t)n * D_SZ + 2 * t]     = f2bf(a0);
    feat[(size_t)n * D_SZ + 2 * t + 1] = f2bf(a1);
    float4 iv = *(const float4*)(i3d + (size_t)n * 1024 + t * 4);
    unsigned short o[4] = {f2bf(iv.x), f2bf(iv.y), f2bf(iv.z), f2bf(iv.w)};
    *(uint2*)(feat + (size_t)n * D_SZ + 512 + t * 4) = *(const uint2*)o;
}

// ---------------------------------------------------------------------------
// p[n, j] = feat[n,:] @ Wr_f-row(j); j<512 -> Wr1 row j, j>=512 -> Wr2 row j-512
// ---------------------------------------------------------------------------
__global__ __launch_bounds__(256) void k_pgemm_valu(
    const unsigned short* __restrict__ feat,  // (1280, 1536) bf16 (ws)
    const float* __restrict__ Wrf,            // (512, 3072) fp32
    float* __restrict__ p)                    // (1280, 1024) fp32
{
    __shared__ __align__(16) float As[64 * LDV];
    __shared__ __align__(16) float Bs[64 * LDV];
    const int t = threadIdx.x;
    const int tx = t & 15, ty = t >> 4;
    const int m0 = blockIdx.x * 64, j0 = blockIdx.y * 64;

    float acc[4][4];
#pragma unroll
    for (int i = 0; i < 4; i++)
#pragma unroll
        for (int j = 0; j < 4; j++) acc[i][j] = 0.f;

    for (int k0 = 0; k0 < D_SZ; k0 += 64) {
        __syncthreads();
#pragma unroll
        for (int it = 0; it < 2; it++) {
            int idx = it * 256 + t;
            int row = idx >> 3, cc = idx & 7;
            int4 raw = *(const int4*)(feat + (size_t)(m0 + row) * D_SZ + k0 + cc * 8);
            const unsigned short* s = (const unsigned short*)&raw;
            float4 f0 = {bf2f(s[0]), bf2f(s[1]), bf2f(s[2]), bf2f(s[3])};
            float4 f1 = {bf2f(s[4]), bf2f(s[5]), bf2f(s[6]), bf2f(s[7])};
            *(float4*)(As + row * LDV + cc * 8)     = f0;
            *(float4*)(As + row * LDV + cc * 8 + 4) = f1;
        }
#pragma unroll
        for (int it = 0; it < 4; it++) {
            int idx = it * 256 + t;
            int row = idx >> 4, cc = idx & 15;
            int j = j0 + row;
            const float* src = (j < 512)
                ? (Wrf + (size_t)j * 3072 + k0)
                : (Wrf + (size_t)(j - 512) * 3072 + 1536 + k0);
            *(float4*)(Bs + row * LDV + cc * 4) = *(const float4*)(src + cc * 4);
        }
        __syncthreads();

        for (int k = 0; k < 64; k += 4) {
            float4 a4[4], b4[4];
#pragma unroll
            for (int i = 0; i < 4; i++) a4[i] = *(const float4*)(As + (i * 16 + ty) * LDV + k);
#pragma unroll
            for (int j = 0; j < 4; j++) b4[j] = *(const float4*)(Bs + (j * 16 + tx) * LDV + k);
#pragma unroll
            for (int i = 0; i < 4; i++)
#pragma unroll
                for (int j = 0; j < 4; j++) {
                    acc[i][j] += a4[i].x * b4[j].x;
                    acc[i][j] += a4[i].y * b4[j].y;
                    acc[i][j] += a4[i].z * b4[j].z;
                    acc[i][j] += a4[i].w * b4[j].w;
                }
        }
    }
#pragma unroll
    for (int i = 0; i < 4; i++)
#pragma unroll
        for (int j = 0; j < 4; j++)
            p[(size_t)(m0 + i * 16 + ty) * 1024 + j0 + j * 16 + tx] = acc[i][j];
}

// ---------------------------------------------------------------------------
// e2[b,i,j] = sum_d tanh(p2[b*F+i,d] + p1[b*F+j,d] + hr[b,d]) * war[d]
// ---------------------------------------------------------------------------
__global__ __launch_bounds__(256) void k_e2(
    const float* __restrict__ p,
    const float* __restrict__ hr,
    const float* __restrict__ war,
    float* __restrict__ e2)
{
    const int blk = blockIdx.x;
    const int b = blk / F_SZ, i = blk % F_SZ;
    const int t = threadIdx.x;
    const int w = t >> 6, l = t & 63;
    const int ni = b * F_SZ + i;

    float base[8], warf[8];
    {
        float4 pa = *(const float4*)(p + (size_t)ni * 1024 + 512 + l * 8);
        float4 pb = *(const float4*)(p + (size_t)ni * 1024 + 512 + l * 8 + 4);
        float4 ha = *(const float4*)(hr + b * H_SZ + l * 8);
        float4 hb = *(const float4*)(hr + b * H_SZ + l * 8 + 4);
        base[0] = pa.x + ha.x; base[1] = pa.y + ha.y; base[2] = pa.z + ha.z; base[3] = pa.w + ha.w;
        base[4] = pb.x + hb.x; base[5] = pb.y + hb.y; base[6] = pb.z + hb.z; base[7] = pb.w + hb.w;
        float4 wa = *(const float4*)(war + l * 8);
        float4 wb = *(const float4*)(war + l * 8 + 4);
        warf[0] = wa.x; warf[1] = wa.y; warf[2] = wa.z; warf[3] = wa.w;
        warf[4] = wb.x; warf[5] = wb.y; warf[6] = wb.z; warf[7] = wb.w;
    }

    for (int j = w; j < F_SZ; j += 4) {
        const float* p1r = p + (size_t)(b * F_SZ + j) * 1024;
        float4 va = *(const float4*)(p1r + l * 8);
        float4 vb = *(const float4*)(p1r + l * 8 + 4);
        float pv[8] = {va.x, va.y, va.z, va.w, vb.x, vb.y, vb.z, vb.w};
        float s = 0.f;
#pragma unroll
        for (int u = 0; u < 8; u++) s += tanhf(pv[u] + base[u]) * warf[u];
#pragma unroll
        for (int off = 32; off; off >>= 1) s += __shfl_xor(s, off);
        if (l == 0) e2[(size_t)b * 1600 + i * F_SZ + j] = s;
    }
}

// ---------------------------------------------------------------------------
// per b: softmax over 1600 e2's, rowsum/colsum, then
// out[b] = [ sum_j colsum_j*feat[b,j,:] | sum_i rowsum_i*feat[b,i,:] ]  (FP32 OUT)
// ---------------------------------------------------------------------------
__global__ __launch_bounds__(256) void k_out(
    const float* __restrict__ e2,
    const unsigned short* __restrict__ feat,
    float* __restrict__ out)                   // (32, 3072) FP32
{
    __shared__ float alpha[1600];
    __shared__ float red[4];
    __shared__ float rs[F_SZ], cs[F_SZ];
    const int b = blockIdx.x, t = threadIdx.x;
    const int w = t >> 6, l = t & 63;

    float lm = -1e30f;
    for (int idx = t; idx < 1600; idx += 256) {
        float v = e2[(size_t)b * 1600 + idx];
        alpha[idx] = v;
        lm = fmaxf(lm, v);
    }
#pragma unroll
    for (int off = 32; off; off >>= 1) lm = fmaxf(lm, __shfl_xor(lm, off));
    if (l == 0) red[w] = lm;
    __syncthreads();
    float M = fmaxf(fmaxf(red[0], red[1]), fmaxf(red[2], red[3]));
    __syncthreads();
    float ls = 0.f;
    for (int idx = t; idx < 1600; idx += 256) {
        float ex = expf(alpha[idx] - M);
        alpha[idx] = ex;
        ls += ex;
    }
#pragma unroll
    for (int off = 32; off; off >>= 1) ls += __shfl_xor(ls, off);
    if (l == 0) red[w] = ls;
    __syncthreads();
    float inv = 1.f / (red[0] + red[1] + red[2] + red[3]);

    if (t < F_SZ) {
        float s = 0.f;
        for (int j = 0; j < F_SZ; j++) s += alpha[t * F_SZ + j];
        rs[t] = s * inv;
    } else if (t >= 128 && t < 128 + F_SZ) {
        int j = t - 128;
        float s = 0.f;
        for (int i2 = 0; i2 < F_SZ; i2++) s += alpha[i2 * F_SZ + j];
        cs[j] = s * inv;
    }
    __syncthreads();

    float a1[6] = {0.f,0.f,0.f,0.f,0.f,0.f};
    float a2[6] = {0.f,0.f,0.f,0.f,0.f,0.f};
    for (int r = 0; r < F_SZ; r++) {
        float w1 = cs[r], w2 = rs[r];
        const unsigned short* fr = feat + (size_t)(b * F_SZ + r) * D_SZ;
#pragma unroll
        for (int u = 0; u < 6; u++) {
            float f = bf2f(fr[t + u * 256]);
            a1[u] += w1 * f;
            a2[u] += w2 * f;
        }
    }
#pragma unroll
    for (int u = 0; u < 6; u++) {
        out[(size_t)b * 3072 + t + u * 256]        = a1[u];
        out[(size_t)b * 3072 + 1536 + t + u * 256] = a2[u];
    }
}

// ---------------------------------------------------------------------------
extern "C" void kernel_launch(void* const* d_in, const int* in_sizes, int n_in,
                              void* d_out, int out_size, void* d_ws, size_t ws_size,
                              hipStream_t stream) {
    const float* i3d    = (const float*)d_in[0];
    const float* objf   = (const float*)d_in[1];
    const float* hidden = (const float*)d_in[2];
    const float* Wsf    = (const float*)d_in[3];
    const float* bsf    = (const float*)d_in[4];
    const float* Wsh    = (const float*)d_in[5];
    const float* bsh    = (const float*)d_in[6];
    const float* was    = (const float*)d_in[7];
    const float* Wrf    = (const float*)d_in[8];
    const float* brf    = (const float*)d_in[9];
    const float* Wrh    = (const float*)d_in[10];
    const float* brh    = (const float*)d_in[11];
    const float* war    = (const float*)d_in[12];
    float* out = (float*)d_out;   // reference output dtype is float32

    char* ws = (char*)d_ws;
    float* hs = (float*)(ws);
    float* hr = (float*)(ws + 65536);
    float* e1 = (float*)(ws + 131072);
    float* e2 = (float*)(ws + 315392);
    float* p  = (float*)(ws + 520192);
    unsigned short* feat = (unsigned short*)(ws + 5763072);

    k_hproj<<<dim3(B_SZ), dim3(256), 0, stream>>>(hidden, Wsh, bsh, bsf, Wrh, brh, brf, hs, hr);
    k_e1_valu<<<dim3(M1 / 64), dim3(256), 0, stream>>>(objf, Wsf, was, hs, e1);
    k_softatt<<<dim3(NROW), dim3(256), 0, stream>>>(objf, i3d, e1, feat);
    k_pgemm_valu<<<dim3(NROW / 64, 1024 / 64), dim3(256), 0, stream>>>(feat, Wrf, p);
    k_e2<<<dim3(NROW), dim3(256), 0, stream>>>(p, hr, war, e2);
    k_out<<<dim3(B_SZ), dim3(256), 0, stream>>>(e2, feat, out);
}